// Round 1
// baseline (509.929 us; speedup 1.0000x reference)
//
#include <hip/hip_runtime.h>
#include <math.h>

#define B 8
#define S 1024
#define D 768
#define H 12
#define V 50257
#define DFF 3072
#define HD (H*D)      // 9216
#define SLO 1012      // first s needed (head 11, last 12 positions of y feed x row 1023)
#define NS 12

// workspace layout (float offsets)
#define OFF_EMEAN 0                     // 768   (atomic sum; divide by V on read)
#define OFF_A     768                   // B*NS*D = 73728 (atomic)
#define OFF_GQ    (OFF_A + B*NS*D)      // NS*D = 9216 (unused now; kept for layout)
#define OFF_SC    (OFF_GQ + NS*D)       // NS*S = 12288 (scores -> attn in place)
#define OFF_YV    (OFF_SC + NS*S)       // B*HD = 73728
#define OFF_YO    (OFF_YV + B*HD)       // B*D = 6144
#define OFF_G     (OFF_YO + B*D)        // B*DFF = 24576
#define OFF_X     (OFF_G + B*DFF)       // B*D = 6144

__device__ __forceinline__ float wsum(float v) {
    v += __shfl_xor(v, 1, 64);
    v += __shfl_xor(v, 2, 64);
    v += __shfl_xor(v, 4, 64);
    v += __shfl_xor(v, 8, 64);
    v += __shfl_xor(v, 16, 64);
    v += __shfl_xor(v, 32, 64);
    return v;
}

// ---- K1: column sums of wte (for e_mean). float4 streaming.
// grid 1024 x 192: 12 waves/CU. Explicit 8-deep load batch (named temps) so the
// compiler keeps 8 global_load_dwordx4 in flight per thread (~96KB/CU in flight,
// ~10x the bandwidth-delay product at 900cy HBM latency).
__global__ __launch_bounds__(192) void k1_emean(const float* __restrict__ wte,
                                                float* __restrict__ ws) {
    const float4* __restrict__ wte4 = reinterpret_cast<const float4*>(wte);
    const int c = threadIdx.x;                                // 0..191 (float4 col)
    float4 a0 = {0,0,0,0}, a1 = {0,0,0,0}, a2 = {0,0,0,0}, a3 = {0,0,0,0};
    int v = blockIdx.x;                                       // 0..1023
    for (; v + 7168 < V; v += 8192) {
        float4 t0 = wte4[(size_t)(v)        * 192 + c];
        float4 t1 = wte4[(size_t)(v + 1024) * 192 + c];
        float4 t2 = wte4[(size_t)(v + 2048) * 192 + c];
        float4 t3 = wte4[(size_t)(v + 3072) * 192 + c];
        float4 t4 = wte4[(size_t)(v + 4096) * 192 + c];
        float4 t5 = wte4[(size_t)(v + 5120) * 192 + c];
        float4 t6 = wte4[(size_t)(v + 6144) * 192 + c];
        float4 t7 = wte4[(size_t)(v + 7168) * 192 + c];
        a0.x += t0.x + t4.x; a0.y += t0.y + t4.y; a0.z += t0.z + t4.z; a0.w += t0.w + t4.w;
        a1.x += t1.x + t5.x; a1.y += t1.y + t5.y; a1.z += t1.z + t5.z; a1.w += t1.w + t5.w;
        a2.x += t2.x + t6.x; a2.y += t2.y + t6.y; a2.z += t2.z + t6.z; a2.w += t2.w + t6.w;
        a3.x += t3.x + t7.x; a3.y += t3.y + t7.y; a3.z += t3.z + t7.z; a3.w += t3.w + t7.w;
    }
    for (; v < V; v += 1024) {
        float4 t = wte4[(size_t)v * 192 + c];
        a0.x += t.x; a0.y += t.y; a0.z += t.z; a0.w += t.w;
    }
    a0.x += a1.x + a2.x + a3.x;
    a0.y += a1.y + a2.y + a3.y;
    a0.z += a1.z + a2.z + a3.z;
    a0.w += a1.w + a2.w + a3.w;
    atomicAdd(&ws[OFF_EMEAN + 4 * c + 0], a0.x);
    atomicAdd(&ws[OFF_EMEAN + 4 * c + 1], a0.y);
    atomicAdd(&ws[OFF_EMEAN + 4 * c + 2], a0.z);
    atomicAdd(&ws[OFF_EMEAN + 4 * c + 3], a0.w);
}

// ---- K2b: scores[s12,t] = p[t,:] . (wpe[SLO+s12+1,:]*wq[11,:]*wk[11,:]).
// gq folded in-kernel (12 wpe rows + wq/wk rows are L2-hot broadcasts) — removes
// the k2a launch + workspace round trip. wave per t. grid 256 x 256
__global__ __launch_bounds__(256) void k2b_scores(const float* __restrict__ wpe,
                                                  const float* __restrict__ wq,
                                                  const float* __restrict__ wk,
                                                  float* __restrict__ ws) {
    const int lane = threadIdx.x & 63;
    const int t = (blockIdx.x * 256 + threadIdx.x) >> 6;      // 0..1023
    float4 pw[3];                                             // p[t] * wq[11] * wk[11]
#pragma unroll
    for (int i = 0; i < 3; ++i) {
        int col = 4 * lane + 256 * i;
        float4 p = *reinterpret_cast<const float4*>(wpe + t * D + col);
        float4 q = *reinterpret_cast<const float4*>(wq + 11 * D + col);
        float4 k = *reinterpret_cast<const float4*>(wk + 11 * D + col);
        pw[i].x = p.x * q.x * k.x;
        pw[i].y = p.y * q.y * k.y;
        pw[i].z = p.z * q.z * k.z;
        pw[i].w = p.w * q.w * k.w;
    }
    float acc[12];
#pragma unroll
    for (int s12 = 0; s12 < 12; ++s12) {
        float a = 0.f;
#pragma unroll
        for (int i = 0; i < 3; ++i) {
            float4 g = *reinterpret_cast<const float4*>(wpe + (SLO + s12 + 1) * D + 4 * lane + 256 * i);
            a += pw[i].x * g.x + pw[i].y * g.y + pw[i].z * g.z + pw[i].w * g.w;
        }
        acc[s12] = a;
    }
#pragma unroll
    for (int s12 = 0; s12 < 12; ++s12) acc[s12] = wsum(acc[s12]);
    float v = acc[0];
#pragma unroll
    for (int j = 1; j < 12; ++j) if (lane == j) v = acc[j];
    if (lane < 12) ws[OFF_SC + lane * S + t] = v;
}

// ---- K3: softmax rows (masked t<=s), writes attn in place (0 beyond). grid 12 x 256
__global__ __launch_bounds__(256) void k3_softmax(float* __restrict__ ws) {
    __shared__ float red[256];
    const int s12 = blockIdx.x, tid = threadIdx.x;
    const int n = SLO + s12 + 1;                              // valid t count
    float* sc = ws + OFF_SC + s12 * S;
    float m = -1e30f;
#pragma unroll
    for (int k = 0; k < 4; ++k) { int t = tid + 256 * k; if (t < n) m = fmaxf(m, sc[t]); }
    red[tid] = m; __syncthreads();
    for (int off = 128; off; off >>= 1) { if (tid < off) red[tid] = fmaxf(red[tid], red[tid + off]); __syncthreads(); }
    float mx = red[0]; __syncthreads();
    float sum = 0.f;
#pragma unroll
    for (int k = 0; k < 4; ++k) { int t = tid + 256 * k; if (t < n) sum += expf(sc[t] - mx); }
    red[tid] = sum; __syncthreads();
    for (int off = 128; off; off >>= 1) { if (tid < off) red[tid] += red[tid + off]; __syncthreads(); }
    float inv = 1.0f / red[0];
#pragma unroll
    for (int k = 0; k < 4; ++k) {
        int t = tid + 256 * k;
        sc[t] = (t < n) ? expf(sc[t] - mx) * inv : 0.0f;
    }
}

// ---- K4: A[b,s12,d] += sum_t attn[s12,t]*wte[idx[b,t],d].
// float4 gather: 192 threads cover one full row. 16 t per block -> 512 blocks
// (6 waves/CU, 2x previous) for better L3-gather latency hiding. grid (64 tc, 8 b) x 192.
__global__ __launch_bounds__(192) void k4_accA(const int* __restrict__ idx,
                                               const float* __restrict__ wte,
                                               float* __restrict__ ws) {
    const float4* __restrict__ wte4 = reinterpret_cast<const float4*>(wte);
    __shared__ float wl[16 * 12];
    const int tc = blockIdx.x, b = blockIdx.y, tid = threadIdx.x;
    {
        int tl = tid / 12, s12 = tid % 12;                    // tid < 192 = 16*12
        wl[tid] = ws[OFF_SC + s12 * S + tc * 16 + tl];
    }
    __syncthreads();
    float4 acc[12] = {};
    const int* __restrict__ ib = idx + b * S + tc * 16;
#pragma unroll 4
    for (int tl = 0; tl < 16; ++tl) {
        int row = ib[tl];
        float4 val = wte4[(size_t)row * 192 + tid];
        const float* w = &wl[tl * 12];
#pragma unroll
        for (int s12 = 0; s12 < 12; ++s12) {
            float wv_ = w[s12];
            acc[s12].x += wv_ * val.x;
            acc[s12].y += wv_ * val.y;
            acc[s12].z += wv_ * val.z;
            acc[s12].w += wv_ * val.w;
        }
    }
#pragma unroll
    for (int s12 = 0; s12 < 12; ++s12) {
        float* dst = &ws[OFF_A + (b * NS + s12) * D + 4 * tid];
        atomicAdd(dst + 0, acc[s12].x);
        atomicAdd(dst + 1, acc[s12].y);
        atomicAdd(dst + 2, acc[s12].z);
        atomicAdd(dst + 3, acc[s12].w);
    }
}

// ---- K5: yv[b, s12*768+d] = (A - e_mean)*wv[11,d]*invn[s]*w_lr[11].
// Tail blocks (288..290) do the old k5b: yo[b,d] = sb[d]. grid 291 x 256
__global__ __launch_bounds__(256) void k5_yv(const int* __restrict__ idx,
                                             const float* __restrict__ wte,
                                             const float* __restrict__ wv,
                                             const float* __restrict__ wlr,
                                             float* __restrict__ ws) {
    if (blockIdx.x < 288) {
        int i = blockIdx.x * 256 + threadIdx.x;               // < 73728
        int b = i / HD, f = i % HD, s12 = f / D, d = f % D;
        float em = ws[OFF_EMEAN + d] * (1.0f / V);
        float A  = ws[OFF_A + (b * NS + s12) * D + d];
        float invn = 1.0f / (float)(SLO + s12 + 1);
        ws[OFF_YV + i] = (A - em) * wv[11 * D + d] * invn * wlr[11];
    } else {
        int d = (blockIdx.x - 288) * 256 + threadIdx.x;       // < 768
        float em = ws[OFF_EMEAN + d] * (1.0f / V);
        float s = 0.f;
#pragma unroll
        for (int b = 0; b < 8; ++b) {
            int row = idx[b * S + (S - 1)];
            s += wte[(size_t)row * D + d];
        }
        float sb = (s - 8.0f * em) * (1.0f / (float)S);
#pragma unroll
        for (int b = 0; b < 8; ++b) ws[OFF_YO + b * D + d] = sb;
    }
}

// ---- K6: yo[b,d'] += sum_f yv[b,f]*w_o[d',f].  wave = 2 rows x 1/4 of k. grid 384 x 256
__global__ __launch_bounds__(256) void k6_wo(const float* __restrict__ w_o,
                                             float* __restrict__ ws) {
    const int lane = threadIdx.x & 63;
    const int wid = (blockIdx.x * 256 + threadIdx.x) >> 6;    // 0..1535
    const int kc = wid & 3;
    const int r0 = (wid >> 2) * 2;                            // 0..766
    const int kbase = kc * 2304;
    float acc[2][8] = {{0}};
#pragma unroll
    for (int i = 0; i < 9; ++i) {
        int k = kbase + 4 * lane + 256 * i;
        float4 a0 = *reinterpret_cast<const float4*>(w_o + (size_t)r0 * HD + k);
        float4 a1 = *reinterpret_cast<const float4*>(w_o + (size_t)(r0 + 1) * HD + k);
#pragma unroll
        for (int b = 0; b < 8; ++b) {
            float4 y = *reinterpret_cast<const float4*>(ws + OFF_YV + b * HD + k);
            acc[0][b] += a0.x * y.x + a0.y * y.y + a0.z * y.z + a0.w * y.w;
            acc[1][b] += a1.x * y.x + a1.y * y.y + a1.z * y.z + a1.w * y.w;
        }
    }
#pragma unroll
    for (int r = 0; r < 2; ++r)
#pragma unroll
        for (int b = 0; b < 8; ++b) acc[r][b] = wsum(acc[r][b]);
    float v = acc[0][0];
#pragma unroll
    for (int l = 1; l < 16; ++l) if (lane == l) v = acc[l >> 3][l & 7];
    if (lane < 16) atomicAdd(&ws[OFF_YO + (lane & 7) * D + r0 + (lane >> 3)], v);
}

// ---- K7: g[b,f] = gelu(sum_d yo[b,d]*w1[f,d]).  wave per f. grid 768 x 256
__global__ __launch_bounds__(256) void k7_mlp1(const float* __restrict__ w1,
                                               float* __restrict__ ws) {
    const int lane = threadIdx.x & 63;
    const int f = (blockIdx.x * 256 + threadIdx.x) >> 6;      // 0..3071
    float acc[8] = {0};
#pragma unroll
    for (int i = 0; i < 3; ++i) {
        int dcol = 4 * lane + 256 * i;
        float4 w = *reinterpret_cast<const float4*>(w1 + (size_t)f * D + dcol);
#pragma unroll
        for (int b = 0; b < 8; ++b) {
            float4 y = *reinterpret_cast<const float4*>(ws + OFF_YO + b * D + dcol);
            acc[b] += w.x * y.x + w.y * y.y + w.z * y.z + w.w * y.w;
        }
    }
#pragma unroll
    for (int b = 0; b < 8; ++b) acc[b] = wsum(acc[b]);
    float v = acc[0];
#pragma unroll
    for (int j = 1; j < 8; ++j) if (lane == j) v = acc[j];
    if (lane < 8) {
        float g = 0.5f * v * (1.0f + erff(v * 0.70710678118654752f));
        ws[OFF_G + lane * DFF + f] = g;
    }
}

// ---- K8: x[b,d] = yo[b,d] + sum_f g[b,f]*w2[d,f].  wave per d. grid 192 x 256
__global__ __launch_bounds__(256) void k8_mlp2(const float* __restrict__ w2,
                                               float* __restrict__ ws) {
    const int lane = threadIdx.x & 63;
    const int dd = (blockIdx.x * 256 + threadIdx.x) >> 6;     // 0..767
    float acc[8] = {0};
#pragma unroll
    for (int i = 0; i < 12; ++i) {
        int fcol = 4 * lane + 256 * i;
        float4 w = *reinterpret_cast<const float4*>(w2 + (size_t)dd * DFF + fcol);
#pragma unroll
        for (int b = 0; b < 8; ++b) {
            float4 g = *reinterpret_cast<const float4*>(ws + OFF_G + b * DFF + fcol);
            acc[b] += w.x * g.x + w.y * g.y + w.z * g.z + w.w * g.w;
        }
    }
#pragma unroll
    for (int b = 0; b < 8; ++b) acc[b] = wsum(acc[b]);
    float v = acc[0];
#pragma unroll
    for (int j = 1; j < 8; ++j) if (lane == j) v = acc[j];
    if (lane < 8) ws[OFF_X + lane * D + dd] = ws[OFF_YO + lane * D + dd] + v;
}

// ---- K9: logits[b,j] = x[b,:] . wte[j,:].  wave per row, x in registers. grid 768 x 256
__global__ __launch_bounds__(256) void k9_logits(const float* __restrict__ wte,
                                                 const float* __restrict__ ws,
                                                 float* __restrict__ out) {
    const int lane = threadIdx.x & 63;
    const int wid = (blockIdx.x * 256 + threadIdx.x) >> 6;
    const int NW = gridDim.x * 4;
    float4 xr[8][3];
#pragma unroll
    for (int b = 0; b < 8; ++b)
#pragma unroll
        for (int i = 0; i < 3; ++i)
            xr[b][i] = *reinterpret_cast<const float4*>(ws + OFF_X + b * D + 4 * lane + 256 * i);
    int j = wid;
    float4 w[3];
    if (j < V) {
#pragma unroll
        for (int i = 0; i < 3; ++i)
            w[i] = *reinterpret_cast<const float4*>(wte + (size_t)j * D + 4 * lane + 256 * i);
    }
    while (j < V) {
        int jn = j + NW;
        float4 wn[3];
        if (jn < V) {
#pragma unroll
            for (int i = 0; i < 3; ++i)
                wn[i] = *reinterpret_cast<const float4*>(wte + (size_t)jn * D + 4 * lane + 256 * i);
        }
        float acc[8] = {0};
#pragma unroll
        for (int b = 0; b < 8; ++b) {
#pragma unroll
            for (int i = 0; i < 3; ++i)
                acc[b] += w[i].x * xr[b][i].x + w[i].y * xr[b][i].y +
                          w[i].z * xr[b][i].z + w[i].w * xr[b][i].w;
        }
#pragma unroll
        for (int b = 0; b < 8; ++b) acc[b] = wsum(acc[b]);
        float v = acc[0];
#pragma unroll
        for (int bb = 1; bb < 8; ++bb) if (lane == bb) v = acc[bb];
        if (lane < 8) out[(size_t)lane * V + j] = v;
#pragma unroll
        for (int i = 0; i < 3; ++i) w[i] = wn[i];
        j = jn;
    }
}

extern "C" void kernel_launch(void* const* d_in, const int* in_sizes, int n_in,
                              void* d_out, int out_size, void* d_ws, size_t ws_size,
                              hipStream_t stream) {
    const int*   idx = (const int*)  d_in[0];
    const float* wte = (const float*)d_in[1];
    const float* wpe = (const float*)d_in[2];
    const float* wq  = (const float*)d_in[3];
    const float* wk  = (const float*)d_in[4];
    const float* wv  = (const float*)d_in[5];
    const float* wlr = (const float*)d_in[6];
    const float* w_o = (const float*)d_in[7];
    const float* w1  = (const float*)d_in[8];
    const float* w2  = (const float*)d_in[9];
    float* out = (float*)d_out;
    float* ws  = (float*)d_ws;

    // zero the atomic-accumulated regions (e_mean + A)
    hipMemsetAsync(ws, 0, (size_t)(768 + B * NS * D) * sizeof(float), stream);

    k1_emean  <<<1024,         192, 0, stream>>>(wte, ws);
    k2b_scores<<<256,          256, 0, stream>>>(wpe, wq, wk, ws);
    k3_softmax<<<12,           256, 0, stream>>>(ws);
    k4_accA   <<<dim3(64, 8),  192, 0, stream>>>(idx, wte, ws);
    k5_yv     <<<291,          256, 0, stream>>>(idx, wte, wv, wlr, ws);
    k6_wo     <<<384,          256, 0, stream>>>(w_o, ws);
    k7_mlp1   <<<768,          256, 0, stream>>>(w1, ws);
    k8_mlp2   <<<192,          256, 0, stream>>>(w2, ws);
    k9_logits <<<768,          256, 0, stream>>>(wte, ws, out);
}

// Round 2
// 491.423 us; speedup vs baseline: 1.0377x; 1.0377x over previous
//
#include <hip/hip_runtime.h>
#include <math.h>

#define B 8
#define S 1024
#define D 768
#define H 12
#define V 50257
#define DFF 3072
#define HD (H*D)      // 9216
#define SLO 1012      // first s needed (head 11, last 12 positions of y feed x row 1023)
#define NS 12

// workspace layout (float offsets)
#define OFF_EMEAN 0                     // 768   (atomic sum; divide by V on read)
#define OFF_A     768                   // B*NS*D = 73728 (atomic)
#define OFF_GQ    (OFF_A + B*NS*D)      // NS*D = 9216 (unused now; kept for layout)
#define OFF_SC    (OFF_GQ + NS*D)       // NS*S = 12288 (scores -> attn in place)
#define OFF_YV    (OFF_SC + NS*S)       // B*HD = 73728
#define OFF_YO    (OFF_YV + B*HD)       // B*D = 6144
#define OFF_G     (OFF_YO + B*D)        // B*DFF = 24576
#define OFF_X     (OFF_G + B*DFF)       // B*D = 6144

__device__ __forceinline__ float wsum(float v) {
    v += __shfl_xor(v, 1, 64);
    v += __shfl_xor(v, 2, 64);
    v += __shfl_xor(v, 4, 64);
    v += __shfl_xor(v, 8, 64);
    v += __shfl_xor(v, 16, 64);
    v += __shfl_xor(v, 32, 64);
    return v;
}

// ---- K1: column sums of wte (for e_mean).
// Copy-bench shape: each block streams a CONTIGUOUS 40-row (120KB) span with a
// running pointer; 4-row batches via array temps keep 4 dwordx4 loads in flight.
// grid 1257 x 192 = ~15 waves/CU; in-flight ~60KB/CU >> 9.2KB BDP.
#define K1_ROWS 40
__global__ __launch_bounds__(192) void k1_emean(const float* __restrict__ wte,
                                                float* __restrict__ ws) {
    const int c = threadIdx.x;                                // float4 column 0..191
    int r0 = blockIdx.x * K1_ROWS;
    if (r0 >= V) return;
    int r1 = r0 + K1_ROWS; if (r1 > V) r1 = V;
    const float4* __restrict__ p = reinterpret_cast<const float4*>(wte) + (size_t)r0 * 192 + c;
    float4 a0 = {0,0,0,0}, a1 = {0,0,0,0}, a2 = {0,0,0,0}, a3 = {0,0,0,0};
    int r = r0;
    for (; r + 4 <= r1; r += 4) {
        float4 t[4];
#pragma unroll
        for (int u = 0; u < 4; ++u) t[u] = p[u * 192];
        p += 4 * 192;
        a0.x += t[0].x; a0.y += t[0].y; a0.z += t[0].z; a0.w += t[0].w;
        a1.x += t[1].x; a1.y += t[1].y; a1.z += t[1].z; a1.w += t[1].w;
        a2.x += t[2].x; a2.y += t[2].y; a2.z += t[2].z; a2.w += t[2].w;
        a3.x += t[3].x; a3.y += t[3].y; a3.z += t[3].z; a3.w += t[3].w;
    }
    for (; r < r1; ++r) {
        float4 t = *p; p += 192;
        a0.x += t.x; a0.y += t.y; a0.z += t.z; a0.w += t.w;
    }
    a0.x += a1.x + a2.x + a3.x;
    a0.y += a1.y + a2.y + a3.y;
    a0.z += a1.z + a2.z + a3.z;
    a0.w += a1.w + a2.w + a3.w;
    atomicAdd(&ws[OFF_EMEAN + 4 * c + 0], a0.x);
    atomicAdd(&ws[OFF_EMEAN + 4 * c + 1], a0.y);
    atomicAdd(&ws[OFF_EMEAN + 4 * c + 2], a0.z);
    atomicAdd(&ws[OFF_EMEAN + 4 * c + 3], a0.w);
}

// ---- K2b: scores[s12,t] = p[t,:] . (wpe[SLO+s12+1,:]*wq[11,:]*wk[11,:]).
// gq folded in-kernel (12 wpe rows + wq/wk rows are L2-hot broadcasts). grid 256 x 256
__global__ __launch_bounds__(256) void k2b_scores(const float* __restrict__ wpe,
                                                  const float* __restrict__ wq,
                                                  const float* __restrict__ wk,
                                                  float* __restrict__ ws) {
    const int lane = threadIdx.x & 63;
    const int t = (blockIdx.x * 256 + threadIdx.x) >> 6;      // 0..1023
    float4 pw[3];                                             // p[t] * wq[11] * wk[11]
#pragma unroll
    for (int i = 0; i < 3; ++i) {
        int col = 4 * lane + 256 * i;
        float4 p = *reinterpret_cast<const float4*>(wpe + t * D + col);
        float4 q = *reinterpret_cast<const float4*>(wq + 11 * D + col);
        float4 k = *reinterpret_cast<const float4*>(wk + 11 * D + col);
        pw[i].x = p.x * q.x * k.x;
        pw[i].y = p.y * q.y * k.y;
        pw[i].z = p.z * q.z * k.z;
        pw[i].w = p.w * q.w * k.w;
    }
    float acc[12];
#pragma unroll
    for (int s12 = 0; s12 < 12; ++s12) {
        float a = 0.f;
#pragma unroll
        for (int i = 0; i < 3; ++i) {
            float4 g = *reinterpret_cast<const float4*>(wpe + (SLO + s12 + 1) * D + 4 * lane + 256 * i);
            a += pw[i].x * g.x + pw[i].y * g.y + pw[i].z * g.z + pw[i].w * g.w;
        }
        acc[s12] = a;
    }
#pragma unroll
    for (int s12 = 0; s12 < 12; ++s12) acc[s12] = wsum(acc[s12]);
    float v = acc[0];
#pragma unroll
    for (int j = 1; j < 12; ++j) if (lane == j) v = acc[j];
    if (lane < 12) ws[OFF_SC + lane * S + t] = v;
}

// ---- K3: softmax rows (masked t<=s), writes attn in place (0 beyond). grid 12 x 256
__global__ __launch_bounds__(256) void k3_softmax(float* __restrict__ ws) {
    __shared__ float red[256];
    const int s12 = blockIdx.x, tid = threadIdx.x;
    const int n = SLO + s12 + 1;                              // valid t count
    float* sc = ws + OFF_SC + s12 * S;
    float m = -1e30f;
#pragma unroll
    for (int k = 0; k < 4; ++k) { int t = tid + 256 * k; if (t < n) m = fmaxf(m, sc[t]); }
    red[tid] = m; __syncthreads();
    for (int off = 128; off; off >>= 1) { if (tid < off) red[tid] = fmaxf(red[tid], red[tid + off]); __syncthreads(); }
    float mx = red[0]; __syncthreads();
    float sum = 0.f;
#pragma unroll
    for (int k = 0; k < 4; ++k) { int t = tid + 256 * k; if (t < n) sum += expf(sc[t] - mx); }
    red[tid] = sum; __syncthreads();
    for (int off = 128; off; off >>= 1) { if (tid < off) red[tid] += red[tid + off]; __syncthreads(); }
    float inv = 1.0f / red[0];
#pragma unroll
    for (int k = 0; k < 4; ++k) {
        int t = tid + 256 * k;
        sc[t] = (t < n) ? expf(sc[t] - mx) * inv : 0.0f;
    }
}

// ---- K4: A[b,s12,d] += sum_t attn[s12,t]*wte[idx[b,t],d].
// float4 gather: 192 threads cover one full row. 32 t per block (round-0 geometry:
// atomics halved vs tc=16 — measured +30us regression). grid (32 tc, 8 b) x 192.
__global__ __launch_bounds__(192) void k4_accA(const int* __restrict__ idx,
                                               const float* __restrict__ wte,
                                               float* __restrict__ ws) {
    const float4* __restrict__ wte4 = reinterpret_cast<const float4*>(wte);
    __shared__ float wl[32 * 12];
    const int tc = blockIdx.x, b = blockIdx.y, tid = threadIdx.x;
    for (int i = tid; i < 384; i += 192) {
        int tl = i / 12, s12 = i % 12;
        wl[i] = ws[OFF_SC + s12 * S + tc * 32 + tl];
    }
    __syncthreads();
    float4 acc[12] = {};
    const int* __restrict__ ib = idx + b * S + tc * 32;
#pragma unroll 4
    for (int tl = 0; tl < 32; ++tl) {
        int row = ib[tl];
        float4 val = wte4[(size_t)row * 192 + tid];
        const float* w = &wl[tl * 12];
#pragma unroll
        for (int s12 = 0; s12 < 12; ++s12) {
            float wv_ = w[s12];
            acc[s12].x += wv_ * val.x;
            acc[s12].y += wv_ * val.y;
            acc[s12].z += wv_ * val.z;
            acc[s12].w += wv_ * val.w;
        }
    }
#pragma unroll
    for (int s12 = 0; s12 < 12; ++s12) {
        float* dst = &ws[OFF_A + (b * NS + s12) * D + 4 * tid];
        atomicAdd(dst + 0, acc[s12].x);
        atomicAdd(dst + 1, acc[s12].y);
        atomicAdd(dst + 2, acc[s12].z);
        atomicAdd(dst + 3, acc[s12].w);
    }
}

// ---- K5: yv[b, s12*768+d] = (A - e_mean)*wv[11,d]*invn[s]*w_lr[11].
// Tail blocks (288..290) do the old k5b: yo[b,d] = sb[d]. grid 291 x 256
__global__ __launch_bounds__(256) void k5_yv(const int* __restrict__ idx,
                                             const float* __restrict__ wte,
                                             const float* __restrict__ wv,
                                             const float* __restrict__ wlr,
                                             float* __restrict__ ws) {
    if (blockIdx.x < 288) {
        int i = blockIdx.x * 256 + threadIdx.x;               // < 73728
        int b = i / HD, f = i % HD, s12 = f / D, d = f % D;
        float em = ws[OFF_EMEAN + d] * (1.0f / V);
        float A  = ws[OFF_A + (b * NS + s12) * D + d];
        float invn = 1.0f / (float)(SLO + s12 + 1);
        ws[OFF_YV + i] = (A - em) * wv[11 * D + d] * invn * wlr[11];
    } else {
        int d = (blockIdx.x - 288) * 256 + threadIdx.x;       // < 768
        float em = ws[OFF_EMEAN + d] * (1.0f / V);
        float s = 0.f;
#pragma unroll
        for (int b = 0; b < 8; ++b) {
            int row = idx[b * S + (S - 1)];
            s += wte[(size_t)row * D + d];
        }
        float sb = (s - 8.0f * em) * (1.0f / (float)S);
#pragma unroll
        for (int b = 0; b < 8; ++b) ws[OFF_YO + b * D + d] = sb;
    }
}

// ---- K6: yo[b,d'] += sum_f yv[b,f]*w_o[d',f].  wave = 2 rows x 1/4 of k. grid 384 x 256
__global__ __launch_bounds__(256) void k6_wo(const float* __restrict__ w_o,
                                             float* __restrict__ ws) {
    const int lane = threadIdx.x & 63;
    const int wid = (blockIdx.x * 256 + threadIdx.x) >> 6;    // 0..1535
    const int kc = wid & 3;
    const int r0 = (wid >> 2) * 2;                            // 0..766
    const int kbase = kc * 2304;
    float acc[2][8] = {{0}};
#pragma unroll
    for (int i = 0; i < 9; ++i) {
        int k = kbase + 4 * lane + 256 * i;
        float4 a0 = *reinterpret_cast<const float4*>(w_o + (size_t)r0 * HD + k);
        float4 a1 = *reinterpret_cast<const float4*>(w_o + (size_t)(r0 + 1) * HD + k);
#pragma unroll
        for (int b = 0; b < 8; ++b) {
            float4 y = *reinterpret_cast<const float4*>(ws + OFF_YV + b * HD + k);
            acc[0][b] += a0.x * y.x + a0.y * y.y + a0.z * y.z + a0.w * y.w;
            acc[1][b] += a1.x * y.x + a1.y * y.y + a1.z * y.z + a1.w * y.w;
        }
    }
#pragma unroll
    for (int r = 0; r < 2; ++r)
#pragma unroll
        for (int b = 0; b < 8; ++b) acc[r][b] = wsum(acc[r][b]);
    float v = acc[0][0];
#pragma unroll
    for (int l = 1; l < 16; ++l) if (lane == l) v = acc[l >> 3][l & 7];
    if (lane < 16) atomicAdd(&ws[OFF_YO + (lane & 7) * D + r0 + (lane >> 3)], v);
}

// ---- K7: g[b,f] = gelu(sum_d yo[b,d]*w1[f,d]).  wave per f. grid 768 x 256
__global__ __launch_bounds__(256) void k7_mlp1(const float* __restrict__ w1,
                                               float* __restrict__ ws) {
    const int lane = threadIdx.x & 63;
    const int f = (blockIdx.x * 256 + threadIdx.x) >> 6;      // 0..3071
    float acc[8] = {0};
#pragma unroll
    for (int i = 0; i < 3; ++i) {
        int dcol = 4 * lane + 256 * i;
        float4 w = *reinterpret_cast<const float4*>(w1 + (size_t)f * D + dcol);
#pragma unroll
        for (int b = 0; b < 8; ++b) {
            float4 y = *reinterpret_cast<const float4*>(ws + OFF_YO + b * D + dcol);
            acc[b] += w.x * y.x + w.y * y.y + w.z * y.z + w.w * y.w;
        }
    }
#pragma unroll
    for (int b = 0; b < 8; ++b) acc[b] = wsum(acc[b]);
    float v = acc[0];
#pragma unroll
    for (int j = 1; j < 8; ++j) if (lane == j) v = acc[j];
    if (lane < 8) {
        float g = 0.5f * v * (1.0f + erff(v * 0.70710678118654752f));
        ws[OFF_G + lane * DFF + f] = g;
    }
}

// ---- K8: x[b,d] = yo[b,d] + sum_f g[b,f]*w2[d,f].  wave per d. grid 192 x 256
__global__ __launch_bounds__(256) void k8_mlp2(const float* __restrict__ w2,
                                               float* __restrict__ ws) {
    const int lane = threadIdx.x & 63;
    const int dd = (blockIdx.x * 256 + threadIdx.x) >> 6;     // 0..767
    float acc[8] = {0};
#pragma unroll
    for (int i = 0; i < 12; ++i) {
        int fcol = 4 * lane + 256 * i;
        float4 w = *reinterpret_cast<const float4*>(w2 + (size_t)dd * DFF + fcol);
#pragma unroll
        for (int b = 0; b < 8; ++b) {
            float4 g = *reinterpret_cast<const float4*>(ws + OFF_G + b * DFF + fcol);
            acc[b] += w.x * g.x + w.y * g.y + w.z * g.z + w.w * g.w;
        }
    }
#pragma unroll
    for (int b = 0; b < 8; ++b) acc[b] = wsum(acc[b]);
    float v = acc[0];
#pragma unroll
    for (int j = 1; j < 8; ++j) if (lane == j) v = acc[j];
    if (lane < 8) ws[OFF_X + lane * D + dd] = ws[OFF_YO + lane * D + dd] + v;
}

// ---- K9: logits[b,j] = x[b,:] . wte[j,:].  wave per row, x in registers. grid 768 x 256
__global__ __launch_bounds__(256) void k9_logits(const float* __restrict__ wte,
                                                 const float* __restrict__ ws,
                                                 float* __restrict__ out) {
    const int lane = threadIdx.x & 63;
    const int wid = (blockIdx.x * 256 + threadIdx.x) >> 6;
    const int NW = gridDim.x * 4;
    float4 xr[8][3];
#pragma unroll
    for (int b = 0; b < 8; ++b)
#pragma unroll
        for (int i = 0; i < 3; ++i)
            xr[b][i] = *reinterpret_cast<const float4*>(ws + OFF_X + b * D + 4 * lane + 256 * i);
    int j = wid;
    float4 w[3];
    if (j < V) {
#pragma unroll
        for (int i = 0; i < 3; ++i)
            w[i] = *reinterpret_cast<const float4*>(wte + (size_t)j * D + 4 * lane + 256 * i);
    }
    while (j < V) {
        int jn = j + NW;
        float4 wn[3];
        if (jn < V) {
#pragma unroll
            for (int i = 0; i < 3; ++i)
                wn[i] = *reinterpret_cast<const float4*>(wte + (size_t)jn * D + 4 * lane + 256 * i);
        }
        float acc[8] = {0};
#pragma unroll
        for (int b = 0; b < 8; ++b) {
#pragma unroll
            for (int i = 0; i < 3; ++i)
                acc[b] += w[i].x * xr[b][i].x + w[i].y * xr[b][i].y +
                          w[i].z * xr[b][i].z + w[i].w * xr[b][i].w;
        }
#pragma unroll
        for (int b = 0; b < 8; ++b) acc[b] = wsum(acc[b]);
        float v = acc[0];
#pragma unroll
        for (int bb = 1; bb < 8; ++bb) if (lane == bb) v = acc[bb];
        if (lane < 8) out[(size_t)lane * V + j] = v;
#pragma unroll
        for (int i = 0; i < 3; ++i) w[i] = wn[i];
        j = jn;
    }
}

extern "C" void kernel_launch(void* const* d_in, const int* in_sizes, int n_in,
                              void* d_out, int out_size, void* d_ws, size_t ws_size,
                              hipStream_t stream) {
    const int*   idx = (const int*)  d_in[0];
    const float* wte = (const float*)d_in[1];
    const float* wpe = (const float*)d_in[2];
    const float* wq  = (const float*)d_in[3];
    const float* wk  = (const float*)d_in[4];
    const float* wv  = (const float*)d_in[5];
    const float* wlr = (const float*)d_in[6];
    const float* w_o = (const float*)d_in[7];
    const float* w1  = (const float*)d_in[8];
    const float* w2  = (const float*)d_in[9];
    float* out = (float*)d_out;
    float* ws  = (float*)d_ws;

    // zero the atomic-accumulated regions (e_mean + A)
    hipMemsetAsync(ws, 0, (size_t)(768 + B * NS * D) * sizeof(float), stream);

    k1_emean  <<<(V + K1_ROWS - 1) / K1_ROWS, 192, 0, stream>>>(wte, ws);
    k2b_scores<<<256,          256, 0, stream>>>(wpe, wq, wk, ws);
    k3_softmax<<<12,           256, 0, stream>>>(ws);
    k4_accA   <<<dim3(32, 8),  192, 0, stream>>>(idx, wte, ws);
    k5_yv     <<<291,          256, 0, stream>>>(idx, wte, wv, wlr, ws);
    k6_wo     <<<384,          256, 0, stream>>>(w_o, ws);
    k7_mlp1   <<<768,          256, 0, stream>>>(w1, ws);
    k8_mlp2   <<<192,          256, 0, stream>>>(w2, ws);
    k9_logits <<<768,          256, 0, stream>>>(wte, ws, out);
}

// Round 3
// 426.841 us; speedup vs baseline: 1.1947x; 1.1513x over previous
//
#include <hip/hip_runtime.h>
#include <math.h>

#define B 8
#define S 1024
#define D 768
#define H 12
#define V 50257
#define DFF 3072
#define HD (H*D)      // 9216
#define SLO 1012      // first s needed (head 11, last 12 positions of y feed x row 1023)
#define NS 12

// workspace layout (float offsets)
#define OFF_EMEAN 0                     // 768   (atomic sum; divide by V on read)
#define OFF_A     768                   // B*NS*D = 73728 (atomic)
#define OFF_GQ    (OFF_A + B*NS*D)      // NS*D = 9216 (unused now; kept for layout)
#define OFF_SC    (OFF_GQ + NS*D)       // NS*S = 12288 (scores -> attn in place)
#define OFF_YV    (OFF_SC + NS*S)       // B*HD = 73728
#define OFF_YO    (OFF_YV + B*HD)       // B*D = 6144
#define OFF_G     (OFF_YO + B*D)        // B*DFF = 24576
#define OFF_X     (OFF_G + B*DFF)       // B*D = 6144

typedef float f4 __attribute__((ext_vector_type(4)));

__device__ __forceinline__ float wsum(float v) {
    v += __shfl_xor(v, 1, 64);
    v += __shfl_xor(v, 2, 64);
    v += __shfl_xor(v, 4, 64);
    v += __shfl_xor(v, 8, 64);
    v += __shfl_xor(v, 16, 64);
    v += __shfl_xor(v, 32, 64);
    return v;
}

// ---- K1: column sums of wte (for e_mean).
// Rounds 0-2 showed hipcc serializes the streaming loads regardless of source
// shape (VGPR_Count 20-32, 560-860 GB/s, VALUBusy <1%). Force the pipeline with
// inline asm: 8 global_load_dwordx4 issued back-to-back, one s_waitcnt vmcnt(0)
// tied to the temps via "+v", then the adds. 8KB/wave in flight x 6 waves/CU
// = 48KB/CU >> 9.2KB BDP.
#define K1_BLOCKS 512
#define K1_ROWS   99              // 512*99 = 50688 >= V; 12 full 8-batches + 3 tail
__global__ __launch_bounds__(192) void k1_emean(const float* __restrict__ wte,
                                                float* __restrict__ ws) {
    const int c = threadIdx.x;                                // float4 column 0..191
    int r0 = blockIdx.x * K1_ROWS;
    if (r0 >= V) return;
    int r1 = r0 + K1_ROWS; if (r1 > V) r1 = V;
    const f4* __restrict__ p = reinterpret_cast<const f4*>(wte) + (size_t)r0 * 192 + c;
    f4 a0 = {0,0,0,0}, a1 = {0,0,0,0}, a2 = {0,0,0,0}, a3 = {0,0,0,0};
    int r = r0;
    for (; r + 8 <= r1; r += 8) {
        const f4* q0 = p;
        const f4* q1 = p + 1 * 192;
        const f4* q2 = p + 2 * 192;
        const f4* q3 = p + 3 * 192;
        const f4* q4 = p + 4 * 192;
        const f4* q5 = p + 5 * 192;
        const f4* q6 = p + 6 * 192;
        const f4* q7 = p + 7 * 192;
        f4 t0, t1, t2, t3, t4, t5, t6, t7;
        asm volatile("global_load_dwordx4 %0, %1, off" : "=v"(t0) : "v"(q0));
        asm volatile("global_load_dwordx4 %0, %1, off" : "=v"(t1) : "v"(q1));
        asm volatile("global_load_dwordx4 %0, %1, off" : "=v"(t2) : "v"(q2));
        asm volatile("global_load_dwordx4 %0, %1, off" : "=v"(t3) : "v"(q3));
        asm volatile("global_load_dwordx4 %0, %1, off" : "=v"(t4) : "v"(q4));
        asm volatile("global_load_dwordx4 %0, %1, off" : "=v"(t5) : "v"(q5));
        asm volatile("global_load_dwordx4 %0, %1, off" : "=v"(t6) : "v"(q6));
        asm volatile("global_load_dwordx4 %0, %1, off" : "=v"(t7) : "v"(q7));
        asm volatile("s_waitcnt vmcnt(0)"
                     : "+v"(t0), "+v"(t1), "+v"(t2), "+v"(t3),
                       "+v"(t4), "+v"(t5), "+v"(t6), "+v"(t7)
                     :
                     : "memory");
        __builtin_amdgcn_sched_barrier(0);
        a0 += t0; a1 += t1; a2 += t2; a3 += t3;
        a0 += t4; a1 += t5; a2 += t6; a3 += t7;
        p += 8 * 192;
    }
    for (; r < r1; ++r) {
        f4 t = *p; p += 192;
        a0 += t;
    }
    a0 += a1 + a2 + a3;
    atomicAdd(&ws[OFF_EMEAN + 4 * c + 0], a0[0]);
    atomicAdd(&ws[OFF_EMEAN + 4 * c + 1], a0[1]);
    atomicAdd(&ws[OFF_EMEAN + 4 * c + 2], a0[2]);
    atomicAdd(&ws[OFF_EMEAN + 4 * c + 3], a0[3]);
}

// ---- K2b: scores[s12,t] = p[t,:] . (wpe[SLO+s12+1,:]*wq[11,:]*wk[11,:]).
// gq folded in-kernel (12 wpe rows + wq/wk rows are L2-hot broadcasts). grid 256 x 256
__global__ __launch_bounds__(256) void k2b_scores(const float* __restrict__ wpe,
                                                  const float* __restrict__ wq,
                                                  const float* __restrict__ wk,
                                                  float* __restrict__ ws) {
    const int lane = threadIdx.x & 63;
    const int t = (blockIdx.x * 256 + threadIdx.x) >> 6;      // 0..1023
    float4 pw[3];                                             // p[t] * wq[11] * wk[11]
#pragma unroll
    for (int i = 0; i < 3; ++i) {
        int col = 4 * lane + 256 * i;
        float4 p = *reinterpret_cast<const float4*>(wpe + t * D + col);
        float4 q = *reinterpret_cast<const float4*>(wq + 11 * D + col);
        float4 k = *reinterpret_cast<const float4*>(wk + 11 * D + col);
        pw[i].x = p.x * q.x * k.x;
        pw[i].y = p.y * q.y * k.y;
        pw[i].z = p.z * q.z * k.z;
        pw[i].w = p.w * q.w * k.w;
    }
    float acc[12];
#pragma unroll
    for (int s12 = 0; s12 < 12; ++s12) {
        float a = 0.f;
#pragma unroll
        for (int i = 0; i < 3; ++i) {
            float4 g = *reinterpret_cast<const float4*>(wpe + (SLO + s12 + 1) * D + 4 * lane + 256 * i);
            a += pw[i].x * g.x + pw[i].y * g.y + pw[i].z * g.z + pw[i].w * g.w;
        }
        acc[s12] = a;
    }
#pragma unroll
    for (int s12 = 0; s12 < 12; ++s12) acc[s12] = wsum(acc[s12]);
    float v = acc[0];
#pragma unroll
    for (int j = 1; j < 12; ++j) if (lane == j) v = acc[j];
    if (lane < 12) ws[OFF_SC + lane * S + t] = v;
}

// ---- K3: softmax rows (masked t<=s), writes attn in place (0 beyond). grid 12 x 256
__global__ __launch_bounds__(256) void k3_softmax(float* __restrict__ ws) {
    __shared__ float red[256];
    const int s12 = blockIdx.x, tid = threadIdx.x;
    const int n = SLO + s12 + 1;                              // valid t count
    float* sc = ws + OFF_SC + s12 * S;
    float m = -1e30f;
#pragma unroll
    for (int k = 0; k < 4; ++k) { int t = tid + 256 * k; if (t < n) m = fmaxf(m, sc[t]); }
    red[tid] = m; __syncthreads();
    for (int off = 128; off; off >>= 1) { if (tid < off) red[tid] = fmaxf(red[tid], red[tid + off]); __syncthreads(); }
    float mx = red[0]; __syncthreads();
    float sum = 0.f;
#pragma unroll
    for (int k = 0; k < 4; ++k) { int t = tid + 256 * k; if (t < n) sum += expf(sc[t] - mx); }
    red[tid] = sum; __syncthreads();
    for (int off = 128; off; off >>= 1) { if (tid < off) red[tid] += red[tid + off]; __syncthreads(); }
    float inv = 1.0f / red[0];
#pragma unroll
    for (int k = 0; k < 4; ++k) {
        int t = tid + 256 * k;
        sc[t] = (t < n) ? expf(sc[t] - mx) * inv : 0.0f;
    }
}

// ---- K4: A[b,s12,d] += sum_t attn[s12,t]*wte[idx[b,t],d].
// float4 gather: 192 threads cover one full row. 32 t per block (round-0 geometry:
// atomics halved vs tc=16 — measured +30us regression). grid (32 tc, 8 b) x 192.
__global__ __launch_bounds__(192) void k4_accA(const int* __restrict__ idx,
                                               const float* __restrict__ wte,
                                               float* __restrict__ ws) {
    const float4* __restrict__ wte4 = reinterpret_cast<const float4*>(wte);
    __shared__ float wl[32 * 12];
    const int tc = blockIdx.x, b = blockIdx.y, tid = threadIdx.x;
    for (int i = tid; i < 384; i += 192) {
        int tl = i / 12, s12 = i % 12;
        wl[i] = ws[OFF_SC + s12 * S + tc * 32 + tl];
    }
    __syncthreads();
    float4 acc[12] = {};
    const int* __restrict__ ib = idx + b * S + tc * 32;
#pragma unroll 4
    for (int tl = 0; tl < 32; ++tl) {
        int row = ib[tl];
        float4 val = wte4[(size_t)row * 192 + tid];
        const float* w = &wl[tl * 12];
#pragma unroll
        for (int s12 = 0; s12 < 12; ++s12) {
            float wv_ = w[s12];
            acc[s12].x += wv_ * val.x;
            acc[s12].y += wv_ * val.y;
            acc[s12].z += wv_ * val.z;
            acc[s12].w += wv_ * val.w;
        }
    }
#pragma unroll
    for (int s12 = 0; s12 < 12; ++s12) {
        float* dst = &ws[OFF_A + (b * NS + s12) * D + 4 * tid];
        atomicAdd(dst + 0, acc[s12].x);
        atomicAdd(dst + 1, acc[s12].y);
        atomicAdd(dst + 2, acc[s12].z);
        atomicAdd(dst + 3, acc[s12].w);
    }
}

// ---- K5: yv[b, s12*768+d] = (A - e_mean)*wv[11,d]*invn[s]*w_lr[11].
// Tail blocks (288..290) do the old k5b: yo[b,d] = sb[d]. grid 291 x 256
__global__ __launch_bounds__(256) void k5_yv(const int* __restrict__ idx,
                                             const float* __restrict__ wte,
                                             const float* __restrict__ wv,
                                             const float* __restrict__ wlr,
                                             float* __restrict__ ws) {
    if (blockIdx.x < 288) {
        int i = blockIdx.x * 256 + threadIdx.x;               // < 73728
        int b = i / HD, f = i % HD, s12 = f / D, d = f % D;
        float em = ws[OFF_EMEAN + d] * (1.0f / V);
        float A  = ws[OFF_A + (b * NS + s12) * D + d];
        float invn = 1.0f / (float)(SLO + s12 + 1);
        ws[OFF_YV + i] = (A - em) * wv[11 * D + d] * invn * wlr[11];
    } else {
        int d = (blockIdx.x - 288) * 256 + threadIdx.x;       // < 768
        float em = ws[OFF_EMEAN + d] * (1.0f / V);
        float s = 0.f;
#pragma unroll
        for (int b = 0; b < 8; ++b) {
            int row = idx[b * S + (S - 1)];
            s += wte[(size_t)row * D + d];
        }
        float sb = (s - 8.0f * em) * (1.0f / (float)S);
#pragma unroll
        for (int b = 0; b < 8; ++b) ws[OFF_YO + b * D + d] = sb;
    }
}

// ---- K6: yo[b,d'] += sum_f yv[b,f]*w_o[d',f].  wave = 2 rows x 1/4 of k. grid 384 x 256
__global__ __launch_bounds__(256) void k6_wo(const float* __restrict__ w_o,
                                             float* __restrict__ ws) {
    const int lane = threadIdx.x & 63;
    const int wid = (blockIdx.x * 256 + threadIdx.x) >> 6;    // 0..1535
    const int kc = wid & 3;
    const int r0 = (wid >> 2) * 2;                            // 0..766
    const int kbase = kc * 2304;
    float acc[2][8] = {{0}};
#pragma unroll
    for (int i = 0; i < 9; ++i) {
        int k = kbase + 4 * lane + 256 * i;
        float4 a0 = *reinterpret_cast<const float4*>(w_o + (size_t)r0 * HD + k);
        float4 a1 = *reinterpret_cast<const float4*>(w_o + (size_t)(r0 + 1) * HD + k);
#pragma unroll
        for (int b = 0; b < 8; ++b) {
            float4 y = *reinterpret_cast<const float4*>(ws + OFF_YV + b * HD + k);
            acc[0][b] += a0.x * y.x + a0.y * y.y + a0.z * y.z + a0.w * y.w;
            acc[1][b] += a1.x * y.x + a1.y * y.y + a1.z * y.z + a1.w * y.w;
        }
    }
#pragma unroll
    for (int r = 0; r < 2; ++r)
#pragma unroll
        for (int b = 0; b < 8; ++b) acc[r][b] = wsum(acc[r][b]);
    float v = acc[0][0];
#pragma unroll
    for (int l = 1; l < 16; ++l) if (lane == l) v = acc[l >> 3][l & 7];
    if (lane < 16) atomicAdd(&ws[OFF_YO + (lane & 7) * D + r0 + (lane >> 3)], v);
}

// ---- K7: g[b,f] = gelu(sum_d yo[b,d]*w1[f,d]).  wave per f. grid 768 x 256
__global__ __launch_bounds__(256) void k7_mlp1(const float* __restrict__ w1,
                                               float* __restrict__ ws) {
    const int lane = threadIdx.x & 63;
    const int f = (blockIdx.x * 256 + threadIdx.x) >> 6;      // 0..3071
    float acc[8] = {0};
#pragma unroll
    for (int i = 0; i < 3; ++i) {
        int dcol = 4 * lane + 256 * i;
        float4 w = *reinterpret_cast<const float4*>(w1 + (size_t)f * D + dcol);
#pragma unroll
        for (int b = 0; b < 8; ++b) {
            float4 y = *reinterpret_cast<const float4*>(ws + OFF_YO + b * D + dcol);
            acc[b] += w.x * y.x + w.y * y.y + w.z * y.z + w.w * y.w;
        }
    }
#pragma unroll
    for (int b = 0; b < 8; ++b) acc[b] = wsum(acc[b]);
    float v = acc[0];
#pragma unroll
    for (int j = 1; j < 8; ++j) if (lane == j) v = acc[j];
    if (lane < 8) {
        float g = 0.5f * v * (1.0f + erff(v * 0.70710678118654752f));
        ws[OFF_G + lane * DFF + f] = g;
    }
}

// ---- K8: x[b,d] = yo[b,d] + sum_f g[b,f]*w2[d,f].  wave per d. grid 192 x 256
__global__ __launch_bounds__(256) void k8_mlp2(const float* __restrict__ w2,
                                               float* __restrict__ ws) {
    const int lane = threadIdx.x & 63;
    const int dd = (blockIdx.x * 256 + threadIdx.x) >> 6;     // 0..767
    float acc[8] = {0};
#pragma unroll
    for (int i = 0; i < 12; ++i) {
        int fcol = 4 * lane + 256 * i;
        float4 w = *reinterpret_cast<const float4*>(w2 + (size_t)dd * DFF + fcol);
#pragma unroll
        for (int b = 0; b < 8; ++b) {
            float4 g = *reinterpret_cast<const float4*>(ws + OFF_G + b * DFF + fcol);
            acc[b] += w.x * g.x + w.y * g.y + w.z * g.z + w.w * g.w;
        }
    }
#pragma unroll
    for (int b = 0; b < 8; ++b) acc[b] = wsum(acc[b]);
    float v = acc[0];
#pragma unroll
    for (int j = 1; j < 8; ++j) if (lane == j) v = acc[j];
    if (lane < 8) ws[OFF_X + lane * D + dd] = ws[OFF_YO + lane * D + dd] + v;
}

// ---- K9: logits[b,j] = x[b,:] . wte[j,:].  wave per row, x in registers. grid 768 x 256
__global__ __launch_bounds__(256) void k9_logits(const float* __restrict__ wte,
                                                 const float* __restrict__ ws,
                                                 float* __restrict__ out) {
    const int lane = threadIdx.x & 63;
    const int wid = (blockIdx.x * 256 + threadIdx.x) >> 6;
    const int NW = gridDim.x * 4;
    float4 xr[8][3];
#pragma unroll
    for (int b = 0; b < 8; ++b)
#pragma unroll
        for (int i = 0; i < 3; ++i)
            xr[b][i] = *reinterpret_cast<const float4*>(ws + OFF_X + b * D + 4 * lane + 256 * i);
    int j = wid;
    float4 w[3];
    if (j < V) {
#pragma unroll
        for (int i = 0; i < 3; ++i)
            w[i] = *reinterpret_cast<const float4*>(wte + (size_t)j * D + 4 * lane + 256 * i);
    }
    while (j < V) {
        int jn = j + NW;
        float4 wn[3];
        if (jn < V) {
#pragma unroll
            for (int i = 0; i < 3; ++i)
                wn[i] = *reinterpret_cast<const float4*>(wte + (size_t)jn * D + 4 * lane + 256 * i);
        }
        float acc[8] = {0};
#pragma unroll
        for (int b = 0; b < 8; ++b) {
#pragma unroll
            for (int i = 0; i < 3; ++i)
                acc[b] += w[i].x * xr[b][i].x + w[i].y * xr[b][i].y +
                          w[i].z * xr[b][i].z + w[i].w * xr[b][i].w;
        }
#pragma unroll
        for (int b = 0; b < 8; ++b) acc[b] = wsum(acc[b]);
        float v = acc[0];
#pragma unroll
        for (int bb = 1; bb < 8; ++bb) if (lane == bb) v = acc[bb];
        if (lane < 8) out[(size_t)lane * V + j] = v;
#pragma unroll
        for (int i = 0; i < 3; ++i) w[i] = wn[i];
        j = jn;
    }
}

extern "C" void kernel_launch(void* const* d_in, const int* in_sizes, int n_in,
                              void* d_out, int out_size, void* d_ws, size_t ws_size,
                              hipStream_t stream) {
    const int*   idx = (const int*)  d_in[0];
    const float* wte = (const float*)d_in[1];
    const float* wpe = (const float*)d_in[2];
    const float* wq  = (const float*)d_in[3];
    const float* wk  = (const float*)d_in[4];
    const float* wv  = (const float*)d_in[5];
    const float* wlr = (const float*)d_in[6];
    const float* w_o = (const float*)d_in[7];
    const float* w1  = (const float*)d_in[8];
    const float* w2  = (const float*)d_in[9];
    float* out = (float*)d_out;
    float* ws  = (float*)d_ws;

    // zero the atomic-accumulated regions (e_mean + A)
    hipMemsetAsync(ws, 0, (size_t)(768 + B * NS * D) * sizeof(float), stream);

    k1_emean  <<<K1_BLOCKS,    192, 0, stream>>>(wte, ws);
    k2b_scores<<<256,          256, 0, stream>>>(wpe, wq, wk, ws);
    k3_softmax<<<12,           256, 0, stream>>>(ws);
    k4_accA   <<<dim3(32, 8),  192, 0, stream>>>(idx, wte, ws);
    k5_yv     <<<291,          256, 0, stream>>>(idx, wte, wv, wlr, ws);
    k6_wo     <<<384,          256, 0, stream>>>(w_o, ws);
    k7_mlp1   <<<768,          256, 0, stream>>>(w1, ws);
    k8_mlp2   <<<192,          256, 0, stream>>>(w2, ws);
    k9_logits <<<768,          256, 0, stream>>>(wte, ws, out);
}

// Round 4
// 352.558 us; speedup vs baseline: 1.4464x; 1.2107x over previous
//
#include <hip/hip_runtime.h>
#include <math.h>

#define B 8
#define S 1024
#define D 768
#define H 12
#define V 50257
#define DFF 3072
#define HD (H*D)      // 9216
#define SLO 1012      // first s needed (head 11, last 12 positions of y feed x row 1023)
#define NS 12

// workspace layout (float offsets)
#define OFF_EMEAN 0                     // 768   (atomic sum; divide by V on read)
#define OFF_A     768                   // B*NS*D = 73728 (atomic)
#define OFF_GQ    (OFF_A + B*NS*D)      // NS*D = 9216 (unused now; kept for layout)
#define OFF_SC    (OFF_GQ + NS*D)       // NS*S = 12288 (scores -> attn in place)
#define OFF_YV    (OFF_SC + NS*S)       // B*HD = 73728
#define OFF_YO    (OFF_YV + B*HD)       // B*D = 6144
#define OFF_G     (OFF_YO + B*D)        // B*DFF = 24576
#define OFF_X     (OFF_G + B*DFF)       // B*D = 6144

typedef float f4 __attribute__((ext_vector_type(4)));

__device__ __forceinline__ float wsum(float v) {
    v += __shfl_xor(v, 1, 64);
    v += __shfl_xor(v, 2, 64);
    v += __shfl_xor(v, 4, 64);
    v += __shfl_xor(v, 8, 64);
    v += __shfl_xor(v, 16, 64);
    v += __shfl_xor(v, 32, 64);
    return v;
}

// ---- K14: fused e_mean column-sum (k1 role) + attention gather-accumulate (k4 role).
// Round-3 evidence: 8-deep forced pipeline didn't move k1 (same 1.5 TB/s as 4-deep)
// -> depth is not binding; occupancy is (6 waves/CU, 13%). New shape: 768-thread
// blocks (12 waves), thread = float column, scalar dword loads (256B/instr, fully
// coalesced), contiguous row spans, asm-forced 8-deep. 24 waves/CU.
// k4 fused in as extra blocks: same latency-bound wte traffic, overlaps with k1.
#define K14_K4_BLOCKS 256             // (32 tc, 8 b)
#define K14_K1_BLOCKS 512
#define K1_ROWS 99                    // 512*99 = 50688 >= V
__global__ __launch_bounds__(768) void k14_emean_accA(const int* __restrict__ idx,
                                                      const float* __restrict__ wte,
                                                      float* __restrict__ ws) {
    __shared__ float wl[32 * 12];
    const int bid = blockIdx.x;
    const int tid = threadIdx.x;                              // 0..767 (float column)
    if (bid >= K14_K4_BLOCKS) {
        // ---- k1 role: column sums of wte rows [r0, r1)
        const int kb = bid - K14_K4_BLOCKS;
        int r0 = kb * K1_ROWS;
        if (r0 >= V) return;
        int r1 = r0 + K1_ROWS; if (r1 > V) r1 = V;
        const float* __restrict__ p = wte + (size_t)r0 * D + tid;
        float a0 = 0.f, a1 = 0.f, a2 = 0.f, a3 = 0.f;
        int r = r0;
        for (; r + 8 <= r1; r += 8) {
            const float* q0 = p;
            const float* q1 = p + 1 * D;
            const float* q2 = p + 2 * D;
            const float* q3 = p + 3 * D;
            const float* q4 = p + 4 * D;
            const float* q5 = p + 5 * D;
            const float* q6 = p + 6 * D;
            const float* q7 = p + 7 * D;
            float t0, t1, t2, t3, t4, t5, t6, t7;
            asm volatile("global_load_dword %0, %1, off" : "=v"(t0) : "v"(q0));
            asm volatile("global_load_dword %0, %1, off" : "=v"(t1) : "v"(q1));
            asm volatile("global_load_dword %0, %1, off" : "=v"(t2) : "v"(q2));
            asm volatile("global_load_dword %0, %1, off" : "=v"(t3) : "v"(q3));
            asm volatile("global_load_dword %0, %1, off" : "=v"(t4) : "v"(q4));
            asm volatile("global_load_dword %0, %1, off" : "=v"(t5) : "v"(q5));
            asm volatile("global_load_dword %0, %1, off" : "=v"(t6) : "v"(q6));
            asm volatile("global_load_dword %0, %1, off" : "=v"(t7) : "v"(q7));
            asm volatile("s_waitcnt vmcnt(0)"
                         : "+v"(t0), "+v"(t1), "+v"(t2), "+v"(t3),
                           "+v"(t4), "+v"(t5), "+v"(t6), "+v"(t7)
                         :
                         : "memory");
            __builtin_amdgcn_sched_barrier(0);
            a0 += t0 + t4; a1 += t1 + t5; a2 += t2 + t6; a3 += t3 + t7;
            p += 8 * D;
        }
        for (; r < r1; ++r) { a0 += *p; p += D; }
        atomicAdd(&ws[OFF_EMEAN + tid], a0 + a1 + a2 + a3);
    } else {
        // ---- k4 role: A[b,s12,:] += sum_t attn[s12,t]*wte[idx[b,t],:]
        const int tc = bid & 31, b = bid >> 5;
        if (tid < 384) {
            int tl = tid / 12, s12 = tid % 12;
            wl[tid] = ws[OFF_SC + s12 * S + tc * 32 + tl];
        }
        __syncthreads();
        float acc[12] = {0,0,0,0,0,0,0,0,0,0,0,0};
        const int* __restrict__ ib = idx + b * S + tc * 32;
#pragma unroll 4
        for (int tl = 0; tl < 32; ++tl) {
            int row = ib[tl];
            float val = wte[(size_t)row * D + tid];
            const float* w = &wl[tl * 12];
#pragma unroll
            for (int s12 = 0; s12 < 12; ++s12) acc[s12] += w[s12] * val;
        }
#pragma unroll
        for (int s12 = 0; s12 < 12; ++s12)
            atomicAdd(&ws[OFF_A + (b * NS + s12) * D + tid], acc[s12]);
    }
}

// ---- K2b: scores[s12,t] = p[t,:] . (wpe[SLO+s12+1,:]*wq[11,:]*wk[11,:]).
// gq folded in-kernel (12 wpe rows + wq/wk rows are L2-hot broadcasts). grid 256 x 256
__global__ __launch_bounds__(256) void k2b_scores(const float* __restrict__ wpe,
                                                  const float* __restrict__ wq,
                                                  const float* __restrict__ wk,
                                                  float* __restrict__ ws) {
    const int lane = threadIdx.x & 63;
    const int t = (blockIdx.x * 256 + threadIdx.x) >> 6;      // 0..1023
    float4 pw[3];                                             // p[t] * wq[11] * wk[11]
#pragma unroll
    for (int i = 0; i < 3; ++i) {
        int col = 4 * lane + 256 * i;
        float4 p = *reinterpret_cast<const float4*>(wpe + t * D + col);
        float4 q = *reinterpret_cast<const float4*>(wq + 11 * D + col);
        float4 k = *reinterpret_cast<const float4*>(wk + 11 * D + col);
        pw[i].x = p.x * q.x * k.x;
        pw[i].y = p.y * q.y * k.y;
        pw[i].z = p.z * q.z * k.z;
        pw[i].w = p.w * q.w * k.w;
    }
    float acc[12];
#pragma unroll
    for (int s12 = 0; s12 < 12; ++s12) {
        float a = 0.f;
#pragma unroll
        for (int i = 0; i < 3; ++i) {
            float4 g = *reinterpret_cast<const float4*>(wpe + (SLO + s12 + 1) * D + 4 * lane + 256 * i);
            a += pw[i].x * g.x + pw[i].y * g.y + pw[i].z * g.z + pw[i].w * g.w;
        }
        acc[s12] = a;
    }
#pragma unroll
    for (int s12 = 0; s12 < 12; ++s12) acc[s12] = wsum(acc[s12]);
    float v = acc[0];
#pragma unroll
    for (int j = 1; j < 12; ++j) if (lane == j) v = acc[j];
    if (lane < 12) ws[OFF_SC + lane * S + t] = v;
}

// ---- K3: softmax rows (masked t<=s), writes attn in place (0 beyond). grid 12 x 256
__global__ __launch_bounds__(256) void k3_softmax(float* __restrict__ ws) {
    __shared__ float red[256];
    const int s12 = blockIdx.x, tid = threadIdx.x;
    const int n = SLO + s12 + 1;                              // valid t count
    float* sc = ws + OFF_SC + s12 * S;
    float m = -1e30f;
#pragma unroll
    for (int k = 0; k < 4; ++k) { int t = tid + 256 * k; if (t < n) m = fmaxf(m, sc[t]); }
    red[tid] = m; __syncthreads();
    for (int off = 128; off; off >>= 1) { if (tid < off) red[tid] = fmaxf(red[tid], red[tid + off]); __syncthreads(); }
    float mx = red[0]; __syncthreads();
    float sum = 0.f;
#pragma unroll
    for (int k = 0; k < 4; ++k) { int t = tid + 256 * k; if (t < n) sum += expf(sc[t] - mx); }
    red[tid] = sum; __syncthreads();
    for (int off = 128; off; off >>= 1) { if (tid < off) red[tid] += red[tid + off]; __syncthreads(); }
    float inv = 1.0f / red[0];
#pragma unroll
    for (int k = 0; k < 4; ++k) {
        int t = tid + 256 * k;
        sc[t] = (t < n) ? expf(sc[t] - mx) * inv : 0.0f;
    }
}

// ---- K5: yv[b, s12*768+d] = (A - e_mean)*wv[11,d]*invn[s]*w_lr[11].
// Tail blocks (288..290) do the old k5b: yo[b,d] = sb[d]. grid 291 x 256
__global__ __launch_bounds__(256) void k5_yv(const int* __restrict__ idx,
                                             const float* __restrict__ wte,
                                             const float* __restrict__ wv,
                                             const float* __restrict__ wlr,
                                             float* __restrict__ ws) {
    if (blockIdx.x < 288) {
        int i = blockIdx.x * 256 + threadIdx.x;               // < 73728
        int b = i / HD, f = i % HD, s12 = f / D, d = f % D;
        float em = ws[OFF_EMEAN + d] * (1.0f / V);
        float A  = ws[OFF_A + (b * NS + s12) * D + d];
        float invn = 1.0f / (float)(SLO + s12 + 1);
        ws[OFF_YV + i] = (A - em) * wv[11 * D + d] * invn * wlr[11];
    } else {
        int d = (blockIdx.x - 288) * 256 + threadIdx.x;       // < 768
        float em = ws[OFF_EMEAN + d] * (1.0f / V);
        float s = 0.f;
#pragma unroll
        for (int b = 0; b < 8; ++b) {
            int row = idx[b * S + (S - 1)];
            s += wte[(size_t)row * D + d];
        }
        float sb = (s - 8.0f * em) * (1.0f / (float)S);
#pragma unroll
        for (int b = 0; b < 8; ++b) ws[OFF_YO + b * D + d] = sb;
    }
}

// ---- K6: yo[b,d'] += sum_f yv[b,f]*w_o[d',f].  wave = 2 rows x 1/4 of k. grid 384 x 256
__global__ __launch_bounds__(256) void k6_wo(const float* __restrict__ w_o,
                                             float* __restrict__ ws) {
    const int lane = threadIdx.x & 63;
    const int wid = (blockIdx.x * 256 + threadIdx.x) >> 6;    // 0..1535
    const int kc = wid & 3;
    const int r0 = (wid >> 2) * 2;                            // 0..766
    const int kbase = kc * 2304;
    float acc[2][8] = {{0}};
#pragma unroll
    for (int i = 0; i < 9; ++i) {
        int k = kbase + 4 * lane + 256 * i;
        float4 a0 = *reinterpret_cast<const float4*>(w_o + (size_t)r0 * HD + k);
        float4 a1 = *reinterpret_cast<const float4*>(w_o + (size_t)(r0 + 1) * HD + k);
#pragma unroll
        for (int b = 0; b < 8; ++b) {
            float4 y = *reinterpret_cast<const float4*>(ws + OFF_YV + b * HD + k);
            acc[0][b] += a0.x * y.x + a0.y * y.y + a0.z * y.z + a0.w * y.w;
            acc[1][b] += a1.x * y.x + a1.y * y.y + a1.z * y.z + a1.w * y.w;
        }
    }
#pragma unroll
    for (int r = 0; r < 2; ++r)
#pragma unroll
        for (int b = 0; b < 8; ++b) acc[r][b] = wsum(acc[r][b]);
    float v = acc[0][0];
#pragma unroll
    for (int l = 1; l < 16; ++l) if (lane == l) v = acc[l >> 3][l & 7];
    if (lane < 16) atomicAdd(&ws[OFF_YO + (lane & 7) * D + r0 + (lane >> 3)], v);
}

// ---- K7: g[b,f] = gelu(sum_d yo[b,d]*w1[f,d]).  wave per f. grid 768 x 256
__global__ __launch_bounds__(256) void k7_mlp1(const float* __restrict__ w1,
                                               float* __restrict__ ws) {
    const int lane = threadIdx.x & 63;
    const int f = (blockIdx.x * 256 + threadIdx.x) >> 6;      // 0..3071
    float acc[8] = {0};
#pragma unroll
    for (int i = 0; i < 3; ++i) {
        int dcol = 4 * lane + 256 * i;
        float4 w = *reinterpret_cast<const float4*>(w1 + (size_t)f * D + dcol);
#pragma unroll
        for (int b = 0; b < 8; ++b) {
            float4 y = *reinterpret_cast<const float4*>(ws + OFF_YO + b * D + dcol);
            acc[b] += w.x * y.x + w.y * y.y + w.z * y.z + w.w * y.w;
        }
    }
#pragma unroll
    for (int b = 0; b < 8; ++b) acc[b] = wsum(acc[b]);
    float v = acc[0];
#pragma unroll
    for (int j = 1; j < 8; ++j) if (lane == j) v = acc[j];
    if (lane < 8) {
        float g = 0.5f * v * (1.0f + erff(v * 0.70710678118654752f));
        ws[OFF_G + lane * DFF + f] = g;
    }
}

// ---- K8: x[b,d] = yo[b,d] + sum_f g[b,f]*w2[d,f].  wave per d. grid 192 x 256
__global__ __launch_bounds__(256) void k8_mlp2(const float* __restrict__ w2,
                                               float* __restrict__ ws) {
    const int lane = threadIdx.x & 63;
    const int dd = (blockIdx.x * 256 + threadIdx.x) >> 6;     // 0..767
    float acc[8] = {0};
#pragma unroll
    for (int i = 0; i < 12; ++i) {
        int fcol = 4 * lane + 256 * i;
        float4 w = *reinterpret_cast<const float4*>(w2 + (size_t)dd * DFF + fcol);
#pragma unroll
        for (int b = 0; b < 8; ++b) {
            float4 g = *reinterpret_cast<const float4*>(ws + OFF_G + b * DFF + fcol);
            acc[b] += w.x * g.x + w.y * g.y + w.z * g.z + w.w * g.w;
        }
    }
#pragma unroll
    for (int b = 0; b < 8; ++b) acc[b] = wsum(acc[b]);
    float v = acc[0];
#pragma unroll
    for (int j = 1; j < 8; ++j) if (lane == j) v = acc[j];
    if (lane < 8) ws[OFF_X + lane * D + dd] = ws[OFF_YO + lane * D + dd] + v;
}

// ---- K9: logits[b,j] = x[b,:] . wte[j,:].  wave per row, x in registers. grid 768 x 256
__global__ __launch_bounds__(256) void k9_logits(const float* __restrict__ wte,
                                                 const float* __restrict__ ws,
                                                 float* __restrict__ out) {
    const int lane = threadIdx.x & 63;
    const int wid = (blockIdx.x * 256 + threadIdx.x) >> 6;
    const int NW = gridDim.x * 4;
    float4 xr[8][3];
#pragma unroll
    for (int b = 0; b < 8; ++b)
#pragma unroll
        for (int i = 0; i < 3; ++i)
            xr[b][i] = *reinterpret_cast<const float4*>(ws + OFF_X + b * D + 4 * lane + 256 * i);
    int j = wid;
    float4 w[3];
    if (j < V) {
#pragma unroll
        for (int i = 0; i < 3; ++i)
            w[i] = *reinterpret_cast<const float4*>(wte + (size_t)j * D + 4 * lane + 256 * i);
    }
    while (j < V) {
        int jn = j + NW;
        float4 wn[3];
        if (jn < V) {
#pragma unroll
            for (int i = 0; i < 3; ++i)
                wn[i] = *reinterpret_cast<const float4*>(wte + (size_t)jn * D + 4 * lane + 256 * i);
        }
        float acc[8] = {0};
#pragma unroll
        for (int b = 0; b < 8; ++b) {
#pragma unroll
            for (int i = 0; i < 3; ++i)
                acc[b] += w[i].x * xr[b][i].x + w[i].y * xr[b][i].y +
                          w[i].z * xr[b][i].z + w[i].w * xr[b][i].w;
        }
#pragma unroll
        for (int b = 0; b < 8; ++b) acc[b] = wsum(acc[b]);
        float v = acc[0];
#pragma unroll
        for (int bb = 1; bb < 8; ++bb) if (lane == bb) v = acc[bb];
        if (lane < 8) out[(size_t)lane * V + j] = v;
#pragma unroll
        for (int i = 0; i < 3; ++i) w[i] = wn[i];
        j = jn;
    }
}

extern "C" void kernel_launch(void* const* d_in, const int* in_sizes, int n_in,
                              void* d_out, int out_size, void* d_ws, size_t ws_size,
                              hipStream_t stream) {
    const int*   idx = (const int*)  d_in[0];
    const float* wte = (const float*)d_in[1];
    const float* wpe = (const float*)d_in[2];
    const float* wq  = (const float*)d_in[3];
    const float* wk  = (const float*)d_in[4];
    const float* wv  = (const float*)d_in[5];
    const float* wlr = (const float*)d_in[6];
    const float* w_o = (const float*)d_in[7];
    const float* w1  = (const float*)d_in[8];
    const float* w2  = (const float*)d_in[9];
    float* out = (float*)d_out;
    float* ws  = (float*)d_ws;

    // zero the atomic-accumulated regions (e_mean + A)
    hipMemsetAsync(ws, 0, (size_t)(768 + B * NS * D) * sizeof(float), stream);

    k2b_scores<<<256, 256, 0, stream>>>(wpe, wq, wk, ws);
    k3_softmax<<<12,  256, 0, stream>>>(ws);
    k14_emean_accA<<<K14_K4_BLOCKS + K14_K1_BLOCKS, 768, 0, stream>>>(idx, wte, ws);
    k5_yv     <<<291, 256, 0, stream>>>(idx, wte, wv, wlr, ws);
    k6_wo     <<<384, 256, 0, stream>>>(w_o, ws);
    k7_mlp1   <<<768, 256, 0, stream>>>(w1, ws);
    k8_mlp2   <<<192, 256, 0, stream>>>(w2, ws);
    k9_logits <<<768, 256, 0, stream>>>(wte, ws, out);
}

// Round 5
// 336.964 us; speedup vs baseline: 1.5133x; 1.0463x over previous
//
#include <hip/hip_runtime.h>
#include <math.h>

#define B 8
#define S 1024
#define D 768
#define H 12
#define V 50257
#define DFF 3072
#define HD (H*D)      // 9216
#define SLO 1012      // first s needed (head 11, last 12 positions of y feed x row 1023)
#define NS 12

// workspace layout (float offsets)
#define OFF_EMEAN 0                     // 768   (atomic sum; divide by V on read)
#define OFF_A     768                   // B*NS*D = 73728 (atomic)
#define OFF_GQ    (OFF_A + B*NS*D)      // NS*D = 9216 (unused now; kept for layout)
#define OFF_SC    (OFF_GQ + NS*D)       // NS*S = 12288 (scores -> attn in place)
#define OFF_YV    (OFF_SC + NS*S)       // B*HD = 73728
#define OFF_YO    (OFF_YV + B*HD)       // B*D = 6144
#define OFF_G     (OFF_YO + B*D)        // B*DFF = 24576
#define OFF_X     (OFF_G + B*DFF)       // B*D = 6144

typedef float f4 __attribute__((ext_vector_type(4)));

__device__ __forceinline__ float wsum(float v) {
    v += __shfl_xor(v, 1, 64);
    v += __shfl_xor(v, 2, 64);
    v += __shfl_xor(v, 4, 64);
    v += __shfl_xor(v, 8, 64);
    v += __shfl_xor(v, 16, 64);
    v += __shfl_xor(v, 32, 64);
    return v;
}

// ---- K14: fused e_mean column-sum (k1 role) + attention gather-accumulate (k4 role).
// 768-thread blocks (12 waves), thread = float column, scalar dword loads (256B/instr
// per wave, fully coalesced), contiguous row spans, asm-forced 8-deep. ~36 waves/CU.
#define K14_K4_BLOCKS 256             // (32 tc, 8 b)
#define K14_K1_BLOCKS 512
#define K1_ROWS 99                    // 512*99 = 50688 >= V
__global__ __launch_bounds__(768) void k14_emean_accA(const int* __restrict__ idx,
                                                      const float* __restrict__ wte,
                                                      float* __restrict__ ws) {
    __shared__ float wl[32 * 12];
    const int bid = blockIdx.x;
    const int tid = threadIdx.x;                              // 0..767 (float column)
    if (bid >= K14_K4_BLOCKS) {
        // ---- k1 role: column sums of wte rows [r0, r1)
        const int kb = bid - K14_K4_BLOCKS;
        int r0 = kb * K1_ROWS;
        if (r0 >= V) return;
        int r1 = r0 + K1_ROWS; if (r1 > V) r1 = V;
        const float* __restrict__ p = wte + (size_t)r0 * D + tid;
        float a0 = 0.f, a1 = 0.f, a2 = 0.f, a3 = 0.f;
        int r = r0;
        for (; r + 8 <= r1; r += 8) {
            const float* q0 = p;
            const float* q1 = p + 1 * D;
            const float* q2 = p + 2 * D;
            const float* q3 = p + 3 * D;
            const float* q4 = p + 4 * D;
            const float* q5 = p + 5 * D;
            const float* q6 = p + 6 * D;
            const float* q7 = p + 7 * D;
            float t0, t1, t2, t3, t4, t5, t6, t7;
            asm volatile("global_load_dword %0, %1, off" : "=v"(t0) : "v"(q0));
            asm volatile("global_load_dword %0, %1, off" : "=v"(t1) : "v"(q1));
            asm volatile("global_load_dword %0, %1, off" : "=v"(t2) : "v"(q2));
            asm volatile("global_load_dword %0, %1, off" : "=v"(t3) : "v"(q3));
            asm volatile("global_load_dword %0, %1, off" : "=v"(t4) : "v"(q4));
            asm volatile("global_load_dword %0, %1, off" : "=v"(t5) : "v"(q5));
            asm volatile("global_load_dword %0, %1, off" : "=v"(t6) : "v"(q6));
            asm volatile("global_load_dword %0, %1, off" : "=v"(t7) : "v"(q7));
            asm volatile("s_waitcnt vmcnt(0)"
                         : "+v"(t0), "+v"(t1), "+v"(t2), "+v"(t3),
                           "+v"(t4), "+v"(t5), "+v"(t6), "+v"(t7)
                         :
                         : "memory");
            __builtin_amdgcn_sched_barrier(0);
            a0 += t0 + t4; a1 += t1 + t5; a2 += t2 + t6; a3 += t3 + t7;
            p += 8 * D;
        }
        for (; r < r1; ++r) { a0 += *p; p += D; }
        atomicAdd(&ws[OFF_EMEAN + tid], a0 + a1 + a2 + a3);
    } else {
        // ---- k4 role: A[b,s12,:] += sum_t attn[s12,t]*wte[idx[b,t],:]
        const int tc = bid & 31, b = bid >> 5;
        if (tid < 384) {
            int tl = tid / 12, s12 = tid % 12;
            wl[tid] = ws[OFF_SC + s12 * S + tc * 32 + tl];
        }
        __syncthreads();
        float acc[12] = {0,0,0,0,0,0,0,0,0,0,0,0};
        const int* __restrict__ ib = idx + b * S + tc * 32;
#pragma unroll 4
        for (int tl = 0; tl < 32; ++tl) {
            int row = ib[tl];
            float val = wte[(size_t)row * D + tid];
            const float* w = &wl[tl * 12];
#pragma unroll
            for (int s12 = 0; s12 < 12; ++s12) acc[s12] += w[s12] * val;
        }
#pragma unroll
        for (int s12 = 0; s12 < 12; ++s12)
            atomicAdd(&ws[OFF_A + (b * NS + s12) * D + tid], acc[s12]);
    }
}

// ---- K2b: scores[s12,t] = p[t,:] . (wpe[SLO+s12+1,:]*wq[11,:]*wk[11,:]).
// Tail blocks (256..546) zero the atomic regions (em + A) — replaces hipMemsetAsync.
// grid 547 x 256
#define K2B_ZBLOCKS 291               // 291*256 = 74496 = 768 + 73728
__global__ __launch_bounds__(256) void k2b_scores(const float* __restrict__ wpe,
                                                  const float* __restrict__ wq,
                                                  const float* __restrict__ wk,
                                                  float* __restrict__ ws) {
    if (blockIdx.x >= 256) {
        int i = (blockIdx.x - 256) * 256 + threadIdx.x;       // < 74496
        ws[OFF_EMEAN + i] = 0.0f;
        return;
    }
    const int lane = threadIdx.x & 63;
    const int t = (blockIdx.x * 256 + threadIdx.x) >> 6;      // 0..1023
    float4 pw[3];                                             // p[t] * wq[11] * wk[11]
#pragma unroll
    for (int i = 0; i < 3; ++i) {
        int col = 4 * lane + 256 * i;
        float4 p = *reinterpret_cast<const float4*>(wpe + t * D + col);
        float4 q = *reinterpret_cast<const float4*>(wq + 11 * D + col);
        float4 k = *reinterpret_cast<const float4*>(wk + 11 * D + col);
        pw[i].x = p.x * q.x * k.x;
        pw[i].y = p.y * q.y * k.y;
        pw[i].z = p.z * q.z * k.z;
        pw[i].w = p.w * q.w * k.w;
    }
    float acc[12];
#pragma unroll
    for (int s12 = 0; s12 < 12; ++s12) {
        float a = 0.f;
#pragma unroll
        for (int i = 0; i < 3; ++i) {
            float4 g = *reinterpret_cast<const float4*>(wpe + (SLO + s12 + 1) * D + 4 * lane + 256 * i);
            a += pw[i].x * g.x + pw[i].y * g.y + pw[i].z * g.z + pw[i].w * g.w;
        }
        acc[s12] = a;
    }
#pragma unroll
    for (int s12 = 0; s12 < 12; ++s12) acc[s12] = wsum(acc[s12]);
    float v = acc[0];
#pragma unroll
    for (int j = 1; j < 12; ++j) if (lane == j) v = acc[j];
    if (lane < 12) ws[OFF_SC + lane * S + t] = v;
}

// ---- K3: softmax rows (masked t<=s), writes attn in place (0 beyond). grid 12 x 256
__global__ __launch_bounds__(256) void k3_softmax(float* __restrict__ ws) {
    __shared__ float red[256];
    const int s12 = blockIdx.x, tid = threadIdx.x;
    const int n = SLO + s12 + 1;                              // valid t count
    float* sc = ws + OFF_SC + s12 * S;
    float m = -1e30f;
#pragma unroll
    for (int k = 0; k < 4; ++k) { int t = tid + 256 * k; if (t < n) m = fmaxf(m, sc[t]); }
    red[tid] = m; __syncthreads();
    for (int off = 128; off; off >>= 1) { if (tid < off) red[tid] = fmaxf(red[tid], red[tid + off]); __syncthreads(); }
    float mx = red[0]; __syncthreads();
    float sum = 0.f;
#pragma unroll
    for (int k = 0; k < 4; ++k) { int t = tid + 256 * k; if (t < n) sum += expf(sc[t] - mx); }
    red[tid] = sum; __syncthreads();
    for (int off = 128; off; off >>= 1) { if (tid < off) red[tid] += red[tid + off]; __syncthreads(); }
    float inv = 1.0f / red[0];
#pragma unroll
    for (int k = 0; k < 4; ++k) {
        int t = tid + 256 * k;
        sc[t] = (t < n) ? expf(sc[t] - mx) * inv : 0.0f;
    }
}

// ---- K5: yv[b, s12*768+d] = (A - e_mean)*wv[11,d]*invn[s]*w_lr[11].
// Tail blocks (288..290) do the old k5b: yo[b,d] = sb[d]. grid 291 x 256
__global__ __launch_bounds__(256) void k5_yv(const int* __restrict__ idx,
                                             const float* __restrict__ wte,
                                             const float* __restrict__ wv,
                                             const float* __restrict__ wlr,
                                             float* __restrict__ ws) {
    if (blockIdx.x < 288) {
        int i = blockIdx.x * 256 + threadIdx.x;               // < 73728
        int b = i / HD, f = i % HD, s12 = f / D, d = f % D;
        float em = ws[OFF_EMEAN + d] * (1.0f / V);
        float A  = ws[OFF_A + (b * NS + s12) * D + d];
        float invn = 1.0f / (float)(SLO + s12 + 1);
        ws[OFF_YV + i] = (A - em) * wv[11 * D + d] * invn * wlr[11];
    } else {
        int d = (blockIdx.x - 288) * 256 + threadIdx.x;       // < 768
        float em = ws[OFF_EMEAN + d] * (1.0f / V);
        float s = 0.f;
#pragma unroll
        for (int b = 0; b < 8; ++b) {
            int row = idx[b * S + (S - 1)];
            s += wte[(size_t)row * D + d];
        }
        float sb = (s - 8.0f * em) * (1.0f / (float)S);
#pragma unroll
        for (int b = 0; b < 8; ++b) ws[OFF_YO + b * D + d] = sb;
    }
}

// ---- K6: yo[b,d'] += sum_f yv[b,f]*w_o[d',f].
// Wave per (row-pair, kc): 12 k-chunks of 768 floats (3 float4-iters).
// 4608 waves = 18/CU (was 6/CU — latency-hiding pass). grid 1152 x 256
__global__ __launch_bounds__(256) void k6_wo(const float* __restrict__ w_o,
                                             float* __restrict__ ws) {
    const int lane = threadIdx.x & 63;
    const int wid = (blockIdx.x * 256 + threadIdx.x) >> 6;    // 0..4607
    const int kc = wid % 12;
    const int r0 = (wid / 12) * 2;                            // 0..766
    const int kbase = kc * 768;
    float acc[2][8] = {{0}};
#pragma unroll
    for (int i = 0; i < 3; ++i) {
        int k = kbase + 4 * lane + 256 * i;
        float4 a0 = *reinterpret_cast<const float4*>(w_o + (size_t)r0 * HD + k);
        float4 a1 = *reinterpret_cast<const float4*>(w_o + (size_t)(r0 + 1) * HD + k);
#pragma unroll
        for (int b = 0; b < 8; ++b) {
            float4 y = *reinterpret_cast<const float4*>(ws + OFF_YV + b * HD + k);
            acc[0][b] += a0.x * y.x + a0.y * y.y + a0.z * y.z + a0.w * y.w;
            acc[1][b] += a1.x * y.x + a1.y * y.y + a1.z * y.z + a1.w * y.w;
        }
    }
#pragma unroll
    for (int r = 0; r < 2; ++r)
#pragma unroll
        for (int b = 0; b < 8; ++b) acc[r][b] = wsum(acc[r][b]);
    float v = acc[0][0];
#pragma unroll
    for (int l = 1; l < 16; ++l) if (lane == l) v = acc[l >> 3][l & 7];
    if (lane < 16) atomicAdd(&ws[OFF_YO + (lane & 7) * D + r0 + (lane >> 3)], v);
}

// ---- K7: g[b,f] = gelu(sum_d yo[b,d]*w1[f,d]).  wave per f.
// Tail blocks (768..791) init X = yo (k8 accumulates partials into X). grid 792 x 256
__global__ __launch_bounds__(256) void k7_mlp1(const float* __restrict__ w1,
                                               float* __restrict__ ws) {
    if (blockIdx.x >= 768) {
        int i = (blockIdx.x - 768) * 256 + threadIdx.x;       // < 6144
        ws[OFF_X + i] = ws[OFF_YO + i];
        return;
    }
    const int lane = threadIdx.x & 63;
    const int f = (blockIdx.x * 256 + threadIdx.x) >> 6;      // 0..3071
    float acc[8] = {0};
#pragma unroll
    for (int i = 0; i < 3; ++i) {
        int dcol = 4 * lane + 256 * i;
        float4 w = *reinterpret_cast<const float4*>(w1 + (size_t)f * D + dcol);
#pragma unroll
        for (int b = 0; b < 8; ++b) {
            float4 y = *reinterpret_cast<const float4*>(ws + OFF_YO + b * D + dcol);
            acc[b] += w.x * y.x + w.y * y.y + w.z * y.z + w.w * y.w;
        }
    }
#pragma unroll
    for (int b = 0; b < 8; ++b) acc[b] = wsum(acc[b]);
    float v = acc[0];
#pragma unroll
    for (int j = 1; j < 8; ++j) if (lane == j) v = acc[j];
    if (lane < 8) {
        float g = 0.5f * v * (1.0f + erff(v * 0.70710678118654752f));
        ws[OFF_G + lane * DFF + f] = g;
    }
}

// ---- K8: x[b,d] += sum_f g[b,f]*w2[d,f]  (X pre-initialized to yo by k7 tail).
// Wave per (d, fc): 4 f-chunks of 768 (3 iters). 3072 waves = 12/CU (was 3/CU).
// grid 768 x 256
__global__ __launch_bounds__(256) void k8_mlp2(const float* __restrict__ w2,
                                               float* __restrict__ ws) {
    const int lane = threadIdx.x & 63;
    const int wid = (blockIdx.x * 256 + threadIdx.x) >> 6;    // 0..3071
    const int fc = wid & 3;
    const int dd = wid >> 2;                                  // 0..767
    const int fbase = fc * 768;
    float acc[8] = {0};
#pragma unroll
    for (int i = 0; i < 3; ++i) {
        int fcol = fbase + 4 * lane + 256 * i;
        float4 w = *reinterpret_cast<const float4*>(w2 + (size_t)dd * DFF + fcol);
#pragma unroll
        for (int b = 0; b < 8; ++b) {
            float4 g = *reinterpret_cast<const float4*>(ws + OFF_G + b * DFF + fcol);
            acc[b] += w.x * g.x + w.y * g.y + w.z * g.z + w.w * g.w;
        }
    }
#pragma unroll
    for (int b = 0; b < 8; ++b) acc[b] = wsum(acc[b]);
    float v = acc[0];
#pragma unroll
    for (int j = 1; j < 8; ++j) if (lane == j) v = acc[j];
    if (lane < 8) atomicAdd(&ws[OFF_X + lane * D + dd], v);
}

// ---- K9: logits[b,j] = x[b,:] . wte[j,:].  wave per row, x in registers,
// 2-deep row prefetch (~800cy load latency hides under 2 rows of compute).
// grid 768 x 256
__global__ __launch_bounds__(256) void k9_logits(const float* __restrict__ wte,
                                                 const float* __restrict__ ws,
                                                 float* __restrict__ out) {
    const int lane = threadIdx.x & 63;
    const int wid = (blockIdx.x * 256 + threadIdx.x) >> 6;
    const int NW = gridDim.x * 4;
    float4 xr[8][3];
#pragma unroll
    for (int b = 0; b < 8; ++b)
#pragma unroll
        for (int i = 0; i < 3; ++i)
            xr[b][i] = *reinterpret_cast<const float4*>(ws + OFF_X + b * D + 4 * lane + 256 * i);
    float4 w0[3], w1[3];
    if (wid < V) {
#pragma unroll
        for (int i = 0; i < 3; ++i)
            w0[i] = *reinterpret_cast<const float4*>(wte + (size_t)wid * D + 4 * lane + 256 * i);
    }
    if (wid + NW < V) {
#pragma unroll
        for (int i = 0; i < 3; ++i)
            w1[i] = *reinterpret_cast<const float4*>(wte + (size_t)(wid + NW) * D + 4 * lane + 256 * i);
    }
    for (int j = wid; j < V; j += NW) {
        int jn2 = j + 2 * NW;
        float4 wn[3];
        if (jn2 < V) {
#pragma unroll
            for (int i = 0; i < 3; ++i)
                wn[i] = *reinterpret_cast<const float4*>(wte + (size_t)jn2 * D + 4 * lane + 256 * i);
        }
        float acc[8] = {0};
#pragma unroll
        for (int b = 0; b < 8; ++b) {
#pragma unroll
            for (int i = 0; i < 3; ++i)
                acc[b] += w0[i].x * xr[b][i].x + w0[i].y * xr[b][i].y +
                          w0[i].z * xr[b][i].z + w0[i].w * xr[b][i].w;
        }
#pragma unroll
        for (int b = 0; b < 8; ++b) acc[b] = wsum(acc[b]);
        float v = acc[0];
#pragma unroll
        for (int bb = 1; bb < 8; ++bb) if (lane == bb) v = acc[bb];
        if (lane < 8) out[(size_t)lane * V + j] = v;
#pragma unroll
        for (int i = 0; i < 3; ++i) { w0[i] = w1[i]; w1[i] = wn[i]; }
    }
}

extern "C" void kernel_launch(void* const* d_in, const int* in_sizes, int n_in,
                              void* d_out, int out_size, void* d_ws, size_t ws_size,
                              hipStream_t stream) {
    const int*   idx = (const int*)  d_in[0];
    const float* wte = (const float*)d_in[1];
    const float* wpe = (const float*)d_in[2];
    const float* wq  = (const float*)d_in[3];
    const float* wk  = (const float*)d_in[4];
    const float* wv  = (const float*)d_in[5];
    const float* wlr = (const float*)d_in[6];
    const float* w_o = (const float*)d_in[7];
    const float* w1  = (const float*)d_in[8];
    const float* w2  = (const float*)d_in[9];
    float* out = (float*)d_out;
    float* ws  = (float*)d_ws;

    k2b_scores<<<256 + K2B_ZBLOCKS, 256, 0, stream>>>(wpe, wq, wk, ws);
    k3_softmax<<<12,   256, 0, stream>>>(ws);
    k14_emean_accA<<<K14_K4_BLOCKS + K14_K1_BLOCKS, 768, 0, stream>>>(idx, wte, ws);
    k5_yv     <<<291,  256, 0, stream>>>(idx, wte, wv, wlr, ws);
    k6_wo     <<<1152, 256, 0, stream>>>(w_o, ws);
    k7_mlp1   <<<792,  256, 0, stream>>>(w1, ws);
    k8_mlp2   <<<768,  256, 0, stream>>>(w2, ws);
    k9_logits <<<768,  256, 0, stream>>>(wte, ws, out);
}